// Round 9
// baseline (185.855 us; speedup 1.0000x reference)
//
#include <hip/hip_runtime.h>

// mixture/target/noise: (N, 2, C, T, F) float32
#define Nn 4
#define Cc 8
#define Tt 256
#define Ff 513
#define TFs (Tt * Ff)      // 131328
#define NCHUNK 16
#define TCHUNK (Tt / NCHUNK)        // 16 t-steps per chunk, 4 per wave
#define SLAB ((size_t)Ff * 64)      // floats per (inp,n,chunk) slab (64/f)

// Packed per-f layout (64 floats = 256 B):
//   [0..55]  = 28 off-diag pairs (re,im), pair index pp(lo<hi) = lo*7 - lo*(lo-1)/2 + (hi-lo-1)
//   [56..63] = 8 diagonal reals (diag imag is exactly 0 -> not stored)

// ---------------------------------------------------------------------------
// Stage 1: partial covariances (R8 structure, packed 64-float slabs).
// 256-thread block = 4 waves; each wave accumulates 4 t-steps for the same
// 64-f range (every input element read exactly once), processed as TWO
// batches of 32 back-to-back loads (8 KB outstanding per wave; 128 KB/CU at
// 16 resident waves). 2-region LDS reduce (stride 65: conflict-free) + one
// cooperative coalesced store. NOTE: input rows are 2052 B (=4 mod 16) ->
// vector loads along f impossible by alignment; scalar 4 B lanes is optimal.
// Partial layout [inp][n][chunk][f][64]: components of one f contiguous.
// ---------------------------------------------------------------------------
__global__ __launch_bounds__(256) void cov_partial(
    const float* __restrict__ target, const float* __restrict__ noise,
    float* __restrict__ partial)
{
    int tid = threadIdx.x;
    int lane = tid & 63, wave = tid >> 6;
    int f0 = blockIdx.x * 64;
    int f = f0 + lane;
    int fc = f < Ff ? f : (Ff - 1);        // clamp: no early return (barriers!)
    int n = blockIdx.y;
    int z = blockIdx.z;                    // z = chunk*2 + inp
    int inp = z & 1;
    int chunk = z >> 1;

    const float* src = inp ? noise : target;
    const float* bt = src + (size_t)n * 2 * Cc * TFs
                      + (size_t)(chunk * TCHUNK + wave * 4) * Ff + fc;

    float ar[36], ai[36];
#pragma unroll
    for (int p = 0; p < 36; ++p) { ar[p] = 0.f; ai[p] = 0.f; }

#pragma unroll
    for (int tp = 0; tp < 2; ++tp) {       // two t-pairs; 32 loads per batch
        float re0[8], im0[8], re1[8], im1[8];
#pragma unroll
        for (int c = 0; c < 8; ++c) {      // all 32 loads issued back-to-back
            re0[c] = bt[(size_t)c * TFs];
            im0[c] = bt[(size_t)(Cc + c) * TFs];
            re1[c] = bt[(size_t)c * TFs + Ff];
            im1[c] = bt[(size_t)(Cc + c) * TFs + Ff];
        }
        int p = 0;
#pragma unroll
        for (int a = 0; a < 8; ++a) {
#pragma unroll
            for (int b = a; b < 8; ++b, ++p) {
                ar[p] += re0[a] * re0[b] + im0[a] * im0[b];
                if (a != b)                // diagonal imag is exactly 0
                    ai[p] += im0[a] * re0[b] - re0[a] * im0[b];
            }
        }
        p = 0;
#pragma unroll
        for (int a = 0; a < 8; ++a) {
#pragma unroll
            for (int b = a; b < 8; ++b, ++p) {
                ar[p] += re1[a] * re1[b] + im1[a] * im1[b];
                if (a != b)
                    ai[p] += im1[a] * re1[b] - re1[a] * im1[b];
            }
        }
        bt += 2 * Ff;
    }

    // --- 2-region LDS reduce across the 4 waves (packed 64-float rows) ------
    __shared__ float red[2][64][65];       // stride 65 -> conflict-free
    int reg = wave & 1;
    if (wave < 2) {
        int p = 0;
#pragma unroll
        for (int a = 0; a < 8; ++a)
#pragma unroll
            for (int b = a; b < 8; ++b, ++p) {
                if (a == b) {
                    red[reg][lane][56 + a] = ar[p];
                } else {
                    const int pp = a * 7 - a * (a - 1) / 2 + (b - a - 1);
                    red[reg][lane][2 * pp]     = ar[p];
                    red[reg][lane][2 * pp + 1] = ai[p];
                }
            }
    }
    __syncthreads();
    if (wave >= 2) {
        int p = 0;
#pragma unroll
        for (int a = 0; a < 8; ++a)
#pragma unroll
            for (int b = a; b < 8; ++b, ++p) {
                if (a == b) {
                    red[reg][lane][56 + a] += ar[p];
                } else {
                    const int pp = a * 7 - a * (a - 1) / 2 + (b - a - 1);
                    red[reg][lane][2 * pp]     += ar[p];
                    red[reg][lane][2 * pp + 1] += ai[p];
                }
            }
    }
    __syncthreads();

    // --- cooperative coalesced store of the [64 f][64] slab -----------------
    int nf = Ff - f0; if (nf > 64) nf = 64;
    float* dst = partial + (((size_t)inp * Nn + n) * NCHUNK + chunk) * SLAB
                 + (size_t)f0 * 64;
    for (int i = tid; i < nf * 64; i += 256) {
        int fl = i >> 6, j = i & 63;
        dst[i] = red[0][fl][j] + red[1][fl][j];
    }
}

// ---------------------------------------------------------------------------
// Stage 2: chunk-reduce + wave-parallel MVDR solve. 256-thread block = 4
// waves = 4 (n,f) solves per block. Lane (r,c) = entry (r,c); every lane
// float2-loads uniformly from the packed slab (diagonal lanes load their
// even-aligned pair and component-select). Gauss-Jordan with partial
// pivoting on [phiN | phiT] -> B = G = phiN^{-1} phiT; all cross-lane
// traffic via shuffles, zero barriers. wconj stored TRANSPOSED [n][c][f].
// ---------------------------------------------------------------------------
__global__ __launch_bounds__(256) void mvdr_weights(
    const float* __restrict__ partial, const int* __restrict__ ref_ptr,
    float2* __restrict__ wconj)
{
    int tid = threadIdx.x;
    int lane = tid & 63, wave = tid >> 6;
    int f = blockIdx.x * 4 + wave;
    int n = blockIdx.y;
    if (f >= Ff) return;                   // uniform per-wave exit, no barriers

    int r = lane >> 3, c = lane & 7;
    bool diag = (r == c);
    int lo = r < c ? r : c, hi = r < c ? c : r;
    int pp = lo * 7 - lo * (lo - 1) / 2 + (hi - lo - 1);
    int off = diag ? (56 + (r & 6)) : (2 * pp);   // even -> float2-aligned

    const float* pT = partial + ((size_t)(0 * Nn + n) * NCHUNK) * SLAB
                      + (size_t)f * 64 + off;
    const float* pN = partial + ((size_t)(1 * Nn + n) * NCHUNK) * SLAB
                      + (size_t)f * 64 + off;
    float2 sT = make_float2(0.f, 0.f), sN = make_float2(0.f, 0.f);
#pragma unroll
    for (int ch = 0; ch < NCHUNK; ++ch) {
        float2 vT = *(const float2*)(pT + ch * SLAB);
        float2 vN = *(const float2*)(pN + ch * SLAB);
        sT.x += vT.x; sT.y += vT.y;
        sN.x += vN.x; sN.y += vN.y;
    }
    if (diag) {                            // select my diagonal component
        sT.x = (r & 1) ? sT.y : sT.x;  sT.y = 0.f;
        sN.x = (r & 1) ? sN.y : sN.x;  sN.y = 0.f;
    }

    const float invT = 1.0f / (float)Tt;
    const float dl = 0.001f / 1.41421356237309515f;   // 0.001/sqrt(2)
    float sgn = (r > c) ? -1.f : 1.f;                 // Hermitian reconstruction

    float2 a = make_float2(sN.x * invT, sgn * sN.y * invT);
    float2 b = make_float2(sT.x * invT, sgn * sT.y * invT);
    if (diag) { a.x += dl; a.y += dl; }               // complex diagonal loading

    for (int k = 0; k < 8; ++k) {
        // --- argmax |A_{jk}|^2 over j >= k (butterfly) ---
        float mag = (c == k && r >= k) ? (a.x * a.x + a.y * a.y) : -1.f;
        int midx = r;
#pragma unroll
        for (int st = 8; st < 64; st <<= 1) {
            float om = __shfl_xor(mag, st, 64);
            int   oi = __shfl_xor(midx, st, 64);
            if (om > mag) { mag = om; midx = oi; }
        }
        int piv = __shfl(midx, k, 64);

        // --- swap rows k <-> piv ---
        int srcr = (r == k) ? piv : ((r == piv) ? k : r);
        int src = srcr * 8 + c;
        a.x = __shfl(a.x, src, 64); a.y = __shfl(a.y, src, 64);
        b.x = __shfl(b.x, src, 64); b.y = __shfl(b.y, src, 64);

        // --- scale row k by 1/pivot ---
        float pvx = __shfl(a.x, k * 8 + k, 64), pvy = __shfl(a.y, k * 8 + k, 64);
        float d = pvx * pvx + pvy * pvy;
        float ipx = pvx / d, ipy = -pvy / d;
        if (r == k) {
            float2 t = a;
            a = make_float2(t.x * ipx - t.y * ipy, t.x * ipy + t.y * ipx);
            t = b;
            b = make_float2(t.x * ipx - t.y * ipy, t.x * ipy + t.y * ipx);
        }

        // --- eliminate all other rows ---
        float rax = __shfl(a.x, k * 8 + c, 64), ray = __shfl(a.y, k * 8 + c, 64);
        float rbx = __shfl(b.x, k * 8 + c, 64), rby = __shfl(b.y, k * 8 + c, 64);
        float fx  = __shfl(a.x, r * 8 + k, 64), fy  = __shfl(a.y, r * 8 + k, 64);
        if (r != k) {
            a.x -= fx * rax - fy * ray;  a.y -= fx * ray + fy * rax;
            b.x -= fx * rbx - fy * rby;  b.y -= fx * rby + fy * rbx;
        }
    }

    // --- l = trace(G): full-wave sum of diagonal entries of B ---
    float tx = (r == c) ? b.x : 0.f, ty = (r == c) ? b.y : 0.f;
#pragma unroll
    for (int st = 1; st < 64; st <<= 1) {
        tx += __shfl_xor(tx, st, 64);
        ty += __shfl_xor(ty, st, 64);
    }

    int ref = *ref_ptr;
    if (c == ref) {                                   // lane (r, ref) holds G_{r,ref}
        float den = tx * tx + ty * ty;
        float wx = (b.x * tx + b.y * ty) / den;       // W = G[:,ref] / l
        float wy = (b.y * tx - b.x * ty) / den;
        // TRANSPOSED layout: [n][c][f]
        wconj[((size_t)n * 8 + r) * Ff + f] = make_float2(wx, -wy);  // conj(W)
    }
}

// ---------------------------------------------------------------------------
// Stage 3: X_bf(n,t,f) = sum_c conj(W)(n,f,c) * y(n,c,t,f)
// wconj layout [n][c][f]: per-channel load is lane-contiguous. Output is
// never re-read on device -> non-temporal stores (keep L2/LLC warm for the
// next iteration's cov input re-reads).
// ---------------------------------------------------------------------------
__global__ __launch_bounds__(256) void beamform(
    const float* __restrict__ y, const float2* __restrict__ wconj,
    float* __restrict__ out)
{
    int idx = blockIdx.x * 256 + threadIdx.x;   // < N*T*F = 525312
    int n = idx / TFs;
    int rem = idx - n * TFs;
    int t = rem / Ff;
    int f = rem - t * Ff;

    size_t base_re = (size_t)n * 2 * Cc * TFs + (size_t)t * Ff + f;
    size_t base_im = base_re + (size_t)Cc * TFs;
    const float2* w = wconj + (size_t)n * 8 * Ff + f;

    float xr = 0.f, xi = 0.f;
#pragma unroll
    for (int c = 0; c < Cc; ++c) {
        float yre = y[base_re + (size_t)c * TFs];
        float yim = y[base_im + (size_t)c * TFs];
        float2 wc = w[(size_t)c * Ff];
        xr += wc.x * yre - wc.y * yim;
        xi += wc.x * yim + wc.y * yre;
    }
    size_t ob = (size_t)n * 2 * TFs + (size_t)t * Ff + f;
    __builtin_nontemporal_store(xr, &out[ob]);
    __builtin_nontemporal_store(xi, &out[ob + TFs]);
}

extern "C" void kernel_launch(void* const* d_in, const int* in_sizes, int n_in,
                              void* d_out, int out_size, void* d_ws, size_t ws_size,
                              hipStream_t stream) {
    const float* mixture = (const float*)d_in[0];
    const float* target  = (const float*)d_in[1];
    const float* noise   = (const float*)d_in[2];
    const int*   refp    = (const int*)d_in[3];
    float* out = (float*)d_out;

    // partial: 2 * Nn * NCHUNK * Ff * 64 floats = ~16.8 MB (ws is ~256 MB)
    float*  partial = (float*)d_ws;
    float2* wconj = (float2*)((char*)d_ws +
                              (size_t)2 * Nn * NCHUNK * SLAB * sizeof(float));

    cov_partial<<<dim3(9, Nn, NCHUNK * 2), 256, 0, stream>>>(target, noise, partial);
    mvdr_weights<<<dim3((Ff + 3) / 4, Nn), 256, 0, stream>>>(partial, refp, wconj);
    beamform<<<dim3((Nn * TFs) / 256), 256, 0, stream>>>(mixture, wconj, out);
}